// Round 1
// baseline (379.391 us; speedup 1.0000x reference)
//
#include <hip/hip_runtime.h>

#define B_   16
#define C_   128
#define HW_  16384
#define NT_  256

typedef __attribute__((ext_vector_type(4))) float  floatx4;
typedef __attribute__((ext_vector_type(8))) short  short8;
typedef __attribute__((ext_vector_type(4))) short  short4v;

static __device__ __forceinline__ unsigned short f2bf(float f){
  unsigned int u = __float_as_uint(f);
  u += 0x7FFFu + ((u >> 16) & 1u);
  return (unsigned short)(u >> 16);
}
static __device__ __forceinline__ float bf2f(unsigned short h){
  return __uint_as_float(((unsigned int)h) << 16);
}
static __device__ __forceinline__ float elu1(float v){
  return v > 0.f ? v + 1.f : __expf(v);
}

// ---------------- K1: GN1 stats (mean, rstd) per (b, g) ----------------
__global__ __launch_bounds__(256) void k_gn1(const float* __restrict__ x,
                                             float* __restrict__ mean, float* __restrict__ rstd){
  int bg = blockIdx.x;                       // b*32+g ; group = 4 contiguous channels
  const float4* p = (const float4*)(x + (size_t)bg * (4 * HW_));
  float s = 0.f, s2 = 0.f;
  for (int i = threadIdx.x; i < 16384; i += 256){
    float4 v = p[i];
    s  += v.x + v.y + v.z + v.w;
    s2 += v.x*v.x + v.y*v.y + v.z*v.z + v.w*v.w;
  }
  #pragma unroll
  for (int o = 32; o; o >>= 1){ s += __shfl_down(s, o); s2 += __shfl_down(s2, o); }
  __shared__ float r1[4], r2[4];
  int wid = threadIdx.x >> 6;
  if ((threadIdx.x & 63) == 0){ r1[wid] = s; r2[wid] = s2; }
  __syncthreads();
  if (threadIdx.x == 0){
    float S  = r1[0] + r1[1] + r1[2] + r1[3];
    float S2 = r2[0] + r2[1] + r2[2] + r2[3];
    float m = S * (1.f / 65536.f);
    float var = S2 * (1.f / 65536.f) - m * m;
    mean[bg] = m;
    rstd[bg] = rsqrtf(var + 1e-5f);
  }
}

// ------- K1b: fold GN1 into qkv weights (per batch), convert w_out to bf16 -------
__global__ __launch_bounds__(64) void k_fold(const float* __restrict__ wqkv, const float* __restrict__ wout,
    const float* __restrict__ g1w, const float* __restrict__ g1b,
    const float* __restrict__ mean, const float* __restrict__ rstd,
    unsigned short* __restrict__ wqp, float* __restrict__ bias, unsigned short* __restrict__ woutb){
  int i = blockIdx.x, l = threadIdx.x;
  if (i < 6144){
    int b = i / 384, o = i % 384;
    float bsum = 0.f;
    #pragma unroll
    for (int j = 0; j < 2; ++j){
      int c = l * 2 + j;
      int g = c >> 2;
      float m = mean[b*32 + g], r = rstd[b*32 + g];
      float A  = r * g1w[c];
      float Bc = g1b[c] - m * A;
      float wv = wqkv[o*128 + c];
      wqp[((size_t)(b*384 + o))*128 + c] = f2bf(wv * A);
      bsum += wv * Bc;
    }
    #pragma unroll
    for (int o2 = 32; o2; o2 >>= 1) bsum += __shfl_down(bsum, o2);
    if (l == 0) bias[b*384 + o] = bsum;
  } else {
    int r = i - 6144;
    #pragma unroll
    for (int j = 0; j < 2; ++j){ int c = l*2 + j; woutb[r*128 + c] = f2bf(wout[r*128 + c]); }
  }
}

// ------- K2a: qkv = W' @ x + bias (MFMA bf16), elu for q/k, store q(T)/k/v bf16 -------
__global__ __launch_bounds__(512) void k_qkv(const float* __restrict__ x, const unsigned short* __restrict__ wqp,
    const float* __restrict__ bias, unsigned short* __restrict__ qT,
    unsigned short* __restrict__ kG, unsigned short* __restrict__ vG){
  int blk = blockIdx.x;
  int b  = blk >> 6;
  int n0 = (blk & 63) * NT_;
  __shared__ unsigned short XnT[NT_][136];     // [n][c], padded: row 272B (17*16)
  int t = threadIdx.x;
  // stage x tile transposed -> XnT[n][c] bf16 (8-channel gather, one b128 write)
  for (int it = 0; it < 8; ++it){
    int slot = t + it * 512;                   // 4096 slots = 256 n * 16 cgroups
    int n  = slot & 255;
    int cg = slot >> 8;
    const float* src = x + ((size_t)b * C_ + cg * 8) * HW_ + n0 + n;
    short8 pk;
    #pragma unroll
    for (int j = 0; j < 8; ++j) pk[j] = (short)f2bf(src[(size_t)j * HW_]);
    *(short8*)(&XnT[n][cg * 8]) = pk;
  }
  __syncthreads();
  int w = t >> 6, lane = t & 63, lr = lane & 15, lk = lane >> 4;
  int obase = w * 48;                          // wave covers 48 output rows
  short8 afr[3][4];
  float biasr[3][4];
  #pragma unroll
  for (int rt = 0; rt < 3; ++rt){
    int o = obase + rt * 16;
    #pragma unroll
    for (int ks = 0; ks < 4; ++ks)
      afr[rt][ks] = *(const short8*)(wqp + ((size_t)(b*384 + o + lr))*128 + ks*32 + lk*8);
    #pragma unroll
    for (int r = 0; r < 4; ++r) biasr[rt][r] = bias[b*384 + o + lk*4 + r];
  }
  for (int ct = 0; ct < 16; ++ct){
    short8 bfr[4];
    #pragma unroll
    for (int ks = 0; ks < 4; ++ks)
      bfr[ks] = *(const short8*)(&XnT[ct*16 + lr][ks*32 + lk*8]);
    #pragma unroll
    for (int rt = 0; rt < 3; ++rt){
      floatx4 acc = {0.f, 0.f, 0.f, 0.f};
      #pragma unroll
      for (int ks = 0; ks < 4; ++ks)
        acc = __builtin_amdgcn_mfma_f32_16x16x32_bf16(afr[rt][ks], bfr[ks], acc, 0, 0, 0);
      int o0 = obase + rt * 16;
      int n  = n0 + ct * 16 + lr;
      if (o0 < 128){                          // q -> qT[b][n][c] (elu+1), packed dwordx2
        short4v pk;
        #pragma unroll
        for (int r = 0; r < 4; ++r) pk[r] = (short)f2bf(elu1(acc[r] + biasr[rt][r]));
        *(short4v*)(qT + ((size_t)b * HW_ + n) * 128 + o0 + lk * 4) = pk;
      } else if (o0 < 256){                   // k -> [b][c][n] (elu+1)
        #pragma unroll
        for (int r = 0; r < 4; ++r)
          kG[((size_t)b*128 + (o0 - 128) + lk*4 + r) * HW_ + n] = f2bf(elu1(acc[r] + biasr[rt][r]));
      } else {                                // v -> [b][c][n]
        #pragma unroll
        for (int r = 0; r < 4; ++r)
          vG[((size_t)b*128 + (o0 - 256) + lk*4 + r) * HW_ + n] = f2bf(acc[r] + biasr[rt][r]);
      }
    }
  }
}

// ------- K2b: kv/ksum partial reduction over an n-chunk of 128 (MFMA over K=n) -------
__global__ __launch_bounds__(64) void k_kvred(const unsigned short* __restrict__ kG, const unsigned short* __restrict__ vG,
    float* __restrict__ kvpart, float* __restrict__ ksumpart){
  int blk = blockIdx.x;                        // b*512 + hd*128 + nc
  int b  = blk >> 9;
  int hd = (blk >> 7) & 3;
  int nc = blk & 127;
  int nb = nc * 128;
  __shared__ unsigned short kb[32][136];
  __shared__ unsigned short vb[32][136];
  int lane = threadIdx.x;
  for (int i = 0; i < 8; ++i){
    int slot = i * 64 + lane;                  // 512 slots = 32 rows * 16
    int row = slot >> 4, colg = slot & 15;
    *(short8*)(&kb[row][colg*8]) = *(const short8*)(kG + ((size_t)b*128 + hd*32 + row)*HW_ + nb + colg*8);
  }
  for (int i = 0; i < 8; ++i){
    int slot = i * 64 + lane;
    int row = slot >> 4, colg = slot & 15;
    *(short8*)(&vb[row][colg*8]) = *(const short8*)(vG + ((size_t)b*128 + hd*32 + row)*HW_ + nb + colg*8);
  }
  __syncthreads();
  int lr = lane & 15, lk = lane >> 4;
  floatx4 a00={0,0,0,0}, a01={0,0,0,0}, a10={0,0,0,0}, a11={0,0,0,0};
  #pragma unroll
  for (int ks = 0; ks < 4; ++ks){
    short8 ka0 = *(const short8*)(&kb[lr     ][ks*32 + lk*8]);
    short8 ka1 = *(const short8*)(&kb[16 + lr][ks*32 + lk*8]);
    short8 vb0 = *(const short8*)(&vb[lr     ][ks*32 + lk*8]);
    short8 vb1 = *(const short8*)(&vb[16 + lr][ks*32 + lk*8]);
    a00 = __builtin_amdgcn_mfma_f32_16x16x32_bf16(ka0, vb0, a00, 0,0,0);
    a01 = __builtin_amdgcn_mfma_f32_16x16x32_bf16(ka0, vb1, a01, 0,0,0);
    a10 = __builtin_amdgcn_mfma_f32_16x16x32_bf16(ka1, vb0, a10, 0,0,0);
    a11 = __builtin_amdgcn_mfma_f32_16x16x32_bf16(ka1, vb1, a11, 0,0,0);
  }
  float* kvp = kvpart + ((((size_t)b*4 + hd)*128 + nc) << 10);
  #pragma unroll
  for (int r = 0; r < 4; ++r){
    kvp[(lk*4 + r)*32      + lr     ] = a00[r];
    kvp[(lk*4 + r)*32      + 16 + lr] = a01[r];
    kvp[(16 + lk*4 + r)*32 + lr     ] = a10[r];
    kvp[(16 + lk*4 + r)*32 + 16 + lr] = a11[r];
  }
  float s = 0.f;
  int d = lane & 31, half = lane >> 5;
  for (int n = half*64; n < half*64 + 64; ++n) s += bf2f(kb[d][n]);
  s += __shfl_down(s, 32);
  if (lane < 32) ksumpart[(((size_t)b*4 + hd)*128 + nc)*32 + d] = s;
}

// ------- K3: finalize kv, ksum -------
__global__ __launch_bounds__(256) void k_kvfin(const float* __restrict__ kvpart, const float* __restrict__ ksumpart,
    float* __restrict__ kv, float* __restrict__ ksum){
  int bh = blockIdx.x, t = threadIdx.x;       // 64 blocks = (b,hd)
  for (int i = t; i < 1024; i += 256){
    float s = 0.f;
    for (int nc = 0; nc < 128; ++nc) s += kvpart[(((size_t)bh*128) + nc)*1024 + i];
    kv[(size_t)bh*1024 + i] = s;
  }
  if (t < 32){
    float s = 0.f;
    for (int nc = 0; nc < 128; ++nc) s += ksumpart[((size_t)bh*128 + nc)*32 + t];
    ksum[bh*32 + t] = s;
  }
}

// ------- K4: per-pixel attention (VALU) + out-conv (MFMA) + GN2 partials -------
__global__ __launch_bounds__(512) void k_attn(const unsigned short* __restrict__ qT,
    const float* __restrict__ kvG, const float* __restrict__ ksumG,
    const unsigned short* __restrict__ woutb,
    float* __restrict__ hbuf, float* __restrict__ gn2part){
  int blk = blockIdx.x;
  int b  = blk >> 6;
  int n0 = (blk & 63) * NT_;
  __shared__ unsigned short qS[NT_ * 128];     // [n][c] bf16, XOR-swizzled 16B slots
  __shared__ float kvT[4][32][32];             // kvT[h][e][d]
  __shared__ float ksumL[128];
  int t = threadIdx.x;
  for (int it = 0; it < 8; ++it){
    int slot = t + it * 512;                   // 4096 16B-slots
    int n = slot >> 4, sl = slot & 15;
    short8 v = *(const short8*)(qT + ((size_t)b * HW_ + n0 + n) * 128 + ((sl ^ (n & 7)) << 3));
    *(short8*)(qS + slot * 8) = v;
  }
  for (int i = t; i < 4096; i += 512){
    int hd = i >> 10, d = (i >> 5) & 31, e = i & 31;
    kvT[hd][e][d] = kvG[((size_t)b*4 + hd)*1024 + d*32 + e];
  }
  if (t < 128) ksumL[t] = ksumG[b*128 + t];
  __syncthreads();
  {
    int n = t & 255;
    int hbase = (t >> 8) * 2;                  // thread handles 2 heads for one pixel
    float qv[64];
    #pragma unroll
    for (int j = 0; j < 16; ++j){
      int c0 = hbase*32 + j*4;
      short4v pk = *(const short4v*)(qS + n*128 + (((c0 >> 3) ^ (n & 7)) << 3) + (c0 & 7));
      qv[j*4+0] = bf2f((unsigned short)pk[0]); qv[j*4+1] = bf2f((unsigned short)pk[1]);
      qv[j*4+2] = bf2f((unsigned short)pk[2]); qv[j*4+3] = bf2f((unsigned short)pk[3]);
    }
    #pragma unroll
    for (int hh = 0; hh < 2; ++hh){
      int h = hbase + hh;
      float denom = 0.f;
      #pragma unroll
      for (int d = 0; d < 32; ++d) denom += qv[hh*32 + d] * ksumL[h*32 + d];
      float inv = 1.f / (denom + 1e-6f);
      #pragma unroll
      for (int e0 = 0; e0 < 32; e0 += 4){
        float o4[4];
        #pragma unroll
        for (int ee = 0; ee < 4; ++ee){
          float a = 0.f;
          #pragma unroll
          for (int d0 = 0; d0 < 32; d0 += 4){
            floatx4 kk = *(const floatx4*)(&kvT[h][e0 + ee][d0]);
            a += qv[hh*32 + d0    ] * kk[0] + qv[hh*32 + d0 + 1] * kk[1]
               + qv[hh*32 + d0 + 2] * kk[2] + qv[hh*32 + d0 + 3] * kk[3];
          }
          o4[ee] = a * inv;
        }
        short4v pk;
        #pragma unroll
        for (int ee = 0; ee < 4; ++ee) pk[ee] = (short)f2bf(o4[ee]);
        int c0 = h*32 + e0;                    // in-place overwrite of the q slots we own
        *(short4v*)(qS + n*128 + (((c0 >> 3) ^ (n & 7)) << 3) + (c0 & 7)) = pk;
      }
    }
  }
  __syncthreads();
  // GEMM2: h = w_out @ attn
  int w = t >> 6, lane = t & 63, lr = lane & 15, lk = lane >> 4;
  short8 afr[4];
  #pragma unroll
  for (int ks = 0; ks < 4; ++ks)
    afr[ks] = *(const short8*)(woutb + (size_t)(w*16 + lr)*128 + ks*32 + lk*8);
  float gs[4] = {0,0,0,0}, gq[4] = {0,0,0,0};
  for (int ct = 0; ct < 16; ++ct){
    int nr = ct*16 + lr;
    short8 bfr[4];
    #pragma unroll
    for (int ks = 0; ks < 4; ++ks)
      bfr[ks] = *(const short8*)(qS + nr*128 + (((ks*4 + lk) ^ (nr & 7)) << 3));
    floatx4 acc = {0.f, 0.f, 0.f, 0.f};
    #pragma unroll
    for (int ks = 0; ks < 4; ++ks)
      acc = __builtin_amdgcn_mfma_f32_16x16x32_bf16(afr[ks], bfr[ks], acc, 0, 0, 0);
    int nn = n0 + ct*16 + lr;
    #pragma unroll
    for (int r = 0; r < 4; ++r){
      float hv = acc[r];
      hbuf[((size_t)b*128 + w*16 + lk*4 + r) * HW_ + nn] = hv;
      gs[r] += hv; gq[r] += hv * hv;
    }
  }
  #pragma unroll
  for (int m = 1; m < 16; m <<= 1){
    #pragma unroll
    for (int r = 0; r < 4; ++r){ gs[r] += __shfl_xor(gs[r], m); gq[r] += __shfl_xor(gq[r], m); }
  }
  if (lr == 0){
    #pragma unroll
    for (int r = 0; r < 4; ++r){
      int o = w*16 + lk*4 + r;
      gn2part[((size_t)blk*128 + o)*2 + 0] = gs[r];
      gn2part[((size_t)blk*128 + o)*2 + 1] = gq[r];
    }
  }
}

// ------- K5: GN2 stats -------
__global__ __launch_bounds__(64) void k_gn2stats(const float* __restrict__ gn2part,
    float* __restrict__ mean, float* __restrict__ rstd){
  int b = blockIdx.x >> 5, g = blockIdx.x & 31;
  int lane = threadIdx.x;
  float s = 0.f, s2 = 0.f;
  #pragma unroll
  for (int j = 0; j < 4; ++j){
    const float* p = gn2part + (((size_t)(b*64 + lane))*128 + g*4 + j)*2;
    s += p[0]; s2 += p[1];
  }
  #pragma unroll
  for (int o = 32; o; o >>= 1){ s += __shfl_down(s, o); s2 += __shfl_down(s2, o); }
  if (lane == 0){
    float m = s * (1.f / 65536.f);
    float var = s2 * (1.f / 65536.f) - m * m;
    mean[blockIdx.x] = m;
    rstd[blockIdx.x] = rsqrtf(var + 1e-5f);
  }
}

// ------- K6: out = GN2(h) + x   (in-place over d_out which holds h) -------
__global__ __launch_bounds__(256) void k_final(float* hx, const float* __restrict__ x,
    const float* __restrict__ mean, const float* __restrict__ rstd,
    const float* __restrict__ g2w, const float* __restrict__ g2b){
  for (size_t chunk = (size_t)blockIdx.x*256 + threadIdx.x; chunk < 4194304ull; chunk += (size_t)2048*256){
    size_t base = chunk * 8;
    int c  = (int)((base >> 14) & 127);
    int bg = (int)(base >> 21) * 32 + (c >> 2);
    float m = mean[bg], r = rstd[bg];
    float sc = r * g2w[c], sh = g2b[c] - m * sc;
    const float4* xp = (const float4*)(x + base);
    float4* hp = (float4*)(hx + base);
    float4 h0 = hp[0], h1 = hp[1], x0 = xp[0], x1 = xp[1];
    float4 o0, o1;
    o0.x = h0.x*sc + sh + x0.x; o0.y = h0.y*sc + sh + x0.y;
    o0.z = h0.z*sc + sh + x0.z; o0.w = h0.w*sc + sh + x0.w;
    o1.x = h1.x*sc + sh + x1.x; o1.y = h1.y*sc + sh + x1.y;
    o1.z = h1.z*sc + sh + x1.z; o1.w = h1.w*sc + sh + x1.w;
    hp[0] = o0; hp[1] = o1;
  }
}

extern "C" void kernel_launch(void* const* d_in, const int* in_sizes, int n_in,
                              void* d_out, int out_size, void* d_ws, size_t ws_size,
                              hipStream_t stream){
  const float* x    = (const float*)d_in[0];
  const float* g1w  = (const float*)d_in[1];
  const float* g1b  = (const float*)d_in[2];
  const float* wqkv = (const float*)d_in[3];
  const float* wout = (const float*)d_in[4];
  const float* g2w  = (const float*)d_in[5];
  const float* g2b  = (const float*)d_in[6];
  char* ws = (char*)d_ws;
  (void)in_sizes; (void)n_in; (void)out_size; (void)ws_size;

  float* gn1_mean = (float*)(ws + 0);
  float* gn1_rstd = (float*)(ws + 2048);
  float* gn2_mean = (float*)(ws + 4096);
  float* gn2_rstd = (float*)(ws + 6144);
  float* bias     = (float*)(ws + 8192);          // 16*384 f32
  float* ksum     = (float*)(ws + 32768);         // 16*4*32 f32
  float* kv       = (float*)(ws + 40960);         // 16*4*1024 f32
  unsigned short* wqp   = (unsigned short*)(ws + 303104);    // 16*384*128 bf16
  unsigned short* woutb = (unsigned short*)(ws + 1875968);   // 128*128 bf16
  float* kvpart   = (float*)(ws + 1908736);       // 16*4*128*1024 f32 = 32MB
  float* ksumpart = (float*)(ws + 35463168);      // 16*4*128*32 f32
  float* gn2part  = (float*)(ws + 36511744);      // 1024*128*2 f32
  unsigned short* qT = (unsigned short*)(ws + 37560320);     // 16*16384*128 bf16 = 64MB
  unsigned short* kG = (unsigned short*)(ws + 104669184);    // 64MB
  unsigned short* vG = (unsigned short*)(ws + 171778048);    // 64MB
  float* hbuf = (float*)d_out;                    // h lives in d_out, finalized in place

  k_gn1<<<dim3(512), dim3(256), 0, stream>>>(x, gn1_mean, gn1_rstd);
  k_fold<<<dim3(6272), dim3(64), 0, stream>>>(wqkv, wout, g1w, g1b, gn1_mean, gn1_rstd, wqp, bias, woutb);
  k_qkv<<<dim3(1024), dim3(512), 0, stream>>>(x, wqp, bias, qT, kG, vG);
  k_kvred<<<dim3(8192), dim3(64), 0, stream>>>(kG, vG, kvpart, ksumpart);
  k_kvfin<<<dim3(64), dim3(256), 0, stream>>>(kvpart, ksumpart, kv, ksum);
  k_attn<<<dim3(1024), dim3(512), 0, stream>>>(qT, kv, ksum, woutb, hbuf, gn2part);
  k_gn2stats<<<dim3(512), dim3(64), 0, stream>>>(gn2part, gn2_mean, gn2_rstd);
  k_final<<<dim3(2048), dim3(256), 0, stream>>>(hbuf, x, gn2_mean, gn2_rstd, g2w, g2b);
}

// Round 2
// 280.290 us; speedup vs baseline: 1.3536x; 1.3536x over previous
//
#include <hip/hip_runtime.h>

#define B_   16
#define C_   128
#define HW_  16384
#define NT_  256

typedef __attribute__((ext_vector_type(4))) float  floatx4;
typedef __attribute__((ext_vector_type(8))) short  short8;
typedef __attribute__((ext_vector_type(4))) short  short4v;

static __device__ __forceinline__ unsigned short f2bf(float f){
  unsigned int u = __float_as_uint(f);
  u += 0x7FFFu + ((u >> 16) & 1u);
  return (unsigned short)(u >> 16);
}
static __device__ __forceinline__ float bf2f(unsigned short h){
  return __uint_as_float(((unsigned int)h) << 16);
}
static __device__ __forceinline__ float elu1(float v){
  return v > 0.f ? v + 1.f : __expf(v);
}

// ---------------- K1: GN1 stats (mean, rstd) per (b, g) ----------------
__global__ __launch_bounds__(256) void k_gn1(const float* __restrict__ x,
                                             float* __restrict__ mean, float* __restrict__ rstd){
  int bg = blockIdx.x;                       // b*32+g ; group = 4 contiguous channels
  const float4* p = (const float4*)(x + (size_t)bg * (4 * HW_));
  float s = 0.f, s2 = 0.f;
  for (int i = threadIdx.x; i < 16384; i += 256){
    float4 v = p[i];
    s  += v.x + v.y + v.z + v.w;
    s2 += v.x*v.x + v.y*v.y + v.z*v.z + v.w*v.w;
  }
  #pragma unroll
  for (int o = 32; o; o >>= 1){ s += __shfl_down(s, o); s2 += __shfl_down(s2, o); }
  __shared__ float r1[4], r2[4];
  int wid = threadIdx.x >> 6;
  if ((threadIdx.x & 63) == 0){ r1[wid] = s; r2[wid] = s2; }
  __syncthreads();
  if (threadIdx.x == 0){
    float S  = r1[0] + r1[1] + r1[2] + r1[3];
    float S2 = r2[0] + r2[1] + r2[2] + r2[3];
    float m = S * (1.f / 65536.f);
    float var = S2 * (1.f / 65536.f) - m * m;
    mean[bg] = m;
    rstd[bg] = rsqrtf(var + 1e-5f);
  }
}

// ------- K1b: fold GN1 into qkv weights (per batch), convert w_out to bf16 -------
__global__ __launch_bounds__(64) void k_fold(const float* __restrict__ wqkv, const float* __restrict__ wout,
    const float* __restrict__ g1w, const float* __restrict__ g1b,
    const float* __restrict__ mean, const float* __restrict__ rstd,
    unsigned short* __restrict__ wqp, float* __restrict__ bias, unsigned short* __restrict__ woutb){
  int i = blockIdx.x, l = threadIdx.x;
  if (i < 6144){
    int b = i / 384, o = i % 384;
    float bsum = 0.f;
    #pragma unroll
    for (int j = 0; j < 2; ++j){
      int c = l * 2 + j;
      int g = c >> 2;
      float m = mean[b*32 + g], r = rstd[b*32 + g];
      float A  = r * g1w[c];
      float Bc = g1b[c] - m * A;
      float wv = wqkv[o*128 + c];
      wqp[((size_t)(b*384 + o))*128 + c] = f2bf(wv * A);
      bsum += wv * Bc;
    }
    #pragma unroll
    for (int o2 = 32; o2; o2 >>= 1) bsum += __shfl_down(bsum, o2);
    if (l == 0) bias[b*384 + o] = bsum;
  } else {
    int r = i - 6144;
    #pragma unroll
    for (int j = 0; j < 2; ++j){ int c = l*2 + j; woutb[r*128 + c] = f2bf(wout[r*128 + c]); }
  }
}

// ------- K2a: qkv = W' @ x + bias (MFMA bf16), elu for q/k, store q(T)/k/v bf16 -------
__global__ __launch_bounds__(512) void k_qkv(const float* __restrict__ x, const unsigned short* __restrict__ wqp,
    const float* __restrict__ bias, unsigned short* __restrict__ qT,
    unsigned short* __restrict__ kG, unsigned short* __restrict__ vG){
  int blk = blockIdx.x;
  int b  = blk >> 6;
  int n0 = (blk & 63) * NT_;
  __shared__ unsigned short XnT[NT_][136];     // [n][c], padded: row 272B (17*16)
  int t = threadIdx.x;
  for (int it = 0; it < 8; ++it){
    int slot = t + it * 512;                   // 4096 slots = 256 n * 16 cgroups
    int n  = slot & 255;
    int cg = slot >> 8;
    const float* src = x + ((size_t)b * C_ + cg * 8) * HW_ + n0 + n;
    short8 pk;
    #pragma unroll
    for (int j = 0; j < 8; ++j) pk[j] = (short)f2bf(src[(size_t)j * HW_]);
    *(short8*)(&XnT[n][cg * 8]) = pk;
  }
  __syncthreads();
  int w = t >> 6, lane = t & 63, lr = lane & 15, lk = lane >> 4;
  int obase = w * 48;                          // wave covers 48 output rows
  short8 afr[3][4];
  float biasr[3][4];
  #pragma unroll
  for (int rt = 0; rt < 3; ++rt){
    int o = obase + rt * 16;
    #pragma unroll
    for (int ks = 0; ks < 4; ++ks)
      afr[rt][ks] = *(const short8*)(wqp + ((size_t)(b*384 + o + lr))*128 + ks*32 + lk*8);
    #pragma unroll
    for (int r = 0; r < 4; ++r) biasr[rt][r] = bias[b*384 + o + lk*4 + r];
  }
  for (int ct = 0; ct < 16; ++ct){
    short8 bfr[4];
    #pragma unroll
    for (int ks = 0; ks < 4; ++ks)
      bfr[ks] = *(const short8*)(&XnT[ct*16 + lr][ks*32 + lk*8]);
    #pragma unroll
    for (int rt = 0; rt < 3; ++rt){
      floatx4 acc = {0.f, 0.f, 0.f, 0.f};
      #pragma unroll
      for (int ks = 0; ks < 4; ++ks)
        acc = __builtin_amdgcn_mfma_f32_16x16x32_bf16(afr[rt][ks], bfr[ks], acc, 0, 0, 0);
      int o0 = obase + rt * 16;
      int n  = n0 + ct * 16 + lr;
      if (o0 < 128){                          // q -> qT[b][n][c] (elu+1)
        short4v pk;
        #pragma unroll
        for (int r = 0; r < 4; ++r) pk[r] = (short)f2bf(elu1(acc[r] + biasr[rt][r]));
        *(short4v*)(qT + ((size_t)b * HW_ + n) * 128 + o0 + lk * 4) = pk;
      } else if (o0 < 256){                   // k -> [b][c][n] (elu+1)
        #pragma unroll
        for (int r = 0; r < 4; ++r)
          kG[((size_t)b*128 + (o0 - 128) + lk*4 + r) * HW_ + n] = f2bf(elu1(acc[r] + biasr[rt][r]));
      } else {                                // v -> [b][c][n]
        #pragma unroll
        for (int r = 0; r < 4; ++r)
          vG[((size_t)b*128 + (o0 - 256) + lk*4 + r) * HW_ + n] = f2bf(acc[r] + biasr[rt][r]);
      }
    }
  }
}

// ------- K2b: kv/ksum partial reduction, LDS-free, fragments direct from global -------
// grid: 16b x 4hd x 8  blocks of 256 threads; each wave reduces a 512-n chunk.
__global__ __launch_bounds__(256) void k_kvred(const unsigned short* __restrict__ kG, const unsigned short* __restrict__ vG,
    float* __restrict__ kvpart, float* __restrict__ ksumpart){
  int blk = blockIdx.x;
  int b  = blk >> 5;
  int hd = (blk >> 3) & 3;
  int c8 = blk & 7;
  int t = threadIdx.x;
  int wid = t >> 6, lane = t & 63, lr = lane & 15, lk = lane >> 4;
  int chunk = c8 * 4 + wid;                    // 0..31
  int nb = chunk * 512;
  const unsigned short* kbase = kG + ((size_t)b*128 + hd*32) * HW_;
  const unsigned short* vbase = vG + ((size_t)b*128 + hd*32) * HW_;
  short8 ones;
  #pragma unroll
  for (int j = 0; j < 8; ++j) ones[j] = (short)0x3F80;  // bf16 1.0
  floatx4 a00={0,0,0,0}, a01={0,0,0,0}, a10={0,0,0,0}, a11={0,0,0,0};
  floatx4 s0={0,0,0,0}, s1={0,0,0,0};
  for (int kg = 0; kg < 16; ++kg){
    int n0 = nb + kg*32 + lk*8;
    short8 ka0 = *(const short8*)(kbase + (size_t)(lr     ) * HW_ + n0);
    short8 ka1 = *(const short8*)(kbase + (size_t)(16 + lr) * HW_ + n0);
    short8 vb0 = *(const short8*)(vbase + (size_t)(lr     ) * HW_ + n0);
    short8 vb1 = *(const short8*)(vbase + (size_t)(16 + lr) * HW_ + n0);
    a00 = __builtin_amdgcn_mfma_f32_16x16x32_bf16(ka0, vb0, a00, 0,0,0);
    a01 = __builtin_amdgcn_mfma_f32_16x16x32_bf16(ka0, vb1, a01, 0,0,0);
    a10 = __builtin_amdgcn_mfma_f32_16x16x32_bf16(ka1, vb0, a10, 0,0,0);
    a11 = __builtin_amdgcn_mfma_f32_16x16x32_bf16(ka1, vb1, a11, 0,0,0);
    s0  = __builtin_amdgcn_mfma_f32_16x16x32_bf16(ka0, ones, s0, 0,0,0);
    s1  = __builtin_amdgcn_mfma_f32_16x16x32_bf16(ka1, ones, s1, 0,0,0);
  }
  float* kvp = kvpart + ((size_t)((b*4 + hd)*32 + chunk) << 10);
  #pragma unroll
  for (int r = 0; r < 4; ++r){
    kvp[(lk*4 + r)*32      + lr     ] = a00[r];
    kvp[(lk*4 + r)*32      + 16 + lr] = a01[r];
    kvp[(16 + lk*4 + r)*32 + lr     ] = a10[r];
    kvp[(16 + lk*4 + r)*32 + 16 + lr] = a11[r];
  }
  if (lr == 0){
    float* ksp = ksumpart + (size_t)((b*4 + hd)*32 + chunk) * 32;
    #pragma unroll
    for (int r = 0; r < 4; ++r){ ksp[lk*4 + r] = s0[r]; ksp[16 + lk*4 + r] = s1[r]; }
  }
}

// ------- K3: finalize kv/ksum and emit bf16 MFMA A-fragments for k_attn -------
// kvF[b][h][f][lane][j]: f=0,1 -> A[row=e][k=d] = kv[d][ f*16 + (lane&15) ], elem j: d=(lane>>4)*8+j
//                        f=2   -> A[row][k] = ksum[k]
__global__ __launch_bounds__(256) void k_kvfin(const float* __restrict__ kvpart, const float* __restrict__ ksumpart,
    unsigned short* __restrict__ kvF){
  int bh = blockIdx.x, t = threadIdx.x;       // 64 blocks = (b,hd)
  __shared__ float kvL[1024];
  __shared__ float ksumL[32];
  for (int i = t; i < 1024; i += 256){
    float s = 0.f;
    for (int nc = 0; nc < 32; ++nc) s += kvpart[((size_t)(bh*32 + nc) << 10) + i];
    kvL[i] = s;
  }
  if (t < 32){
    float s = 0.f;
    for (int nc = 0; nc < 32; ++nc) s += ksumpart[(size_t)(bh*32 + nc)*32 + t];
    ksumL[t] = s;
  }
  __syncthreads();
  for (int idx = t; idx < 3*512; idx += 256){
    int f = idx >> 9, rem = idx & 511;
    int lane = rem >> 3, j = rem & 7;
    int d = (lane >> 4)*8 + j;
    float v = (f < 2) ? kvL[d*32 + f*16 + (lane & 15)] : ksumL[d];
    kvF[(size_t)(bh*3 + f)*512 + rem] = f2bf(v);
  }
}

// ------- K4: attention via MFMA + out-conv (MFMA) + GN2 partials; h -> bf16 -------
__global__ __launch_bounds__(512, 4) void k_attn(const unsigned short* __restrict__ qT,
    const unsigned short* __restrict__ kvF,
    const unsigned short* __restrict__ woutb,
    unsigned short* __restrict__ hb, float* __restrict__ gn2part){
  int blk = blockIdx.x;
  int b  = blk >> 6;
  int n0 = (blk & 63) * NT_;
  __shared__ unsigned short aS[NT_ * 128];     // [n][c] bf16, XOR-swizzled 16B slots
  int t = threadIdx.x;
  int w = t >> 6, lane = t & 63, lr = lane & 15, lk = lane >> 4;

  // ---- phase 1: P = kv^T @ q^T per head (MFMA), denom via ksum-fragment ----
  const unsigned short* kvFb = kvF + (size_t)b * 12 * 512;
  short8 kvf[4][2], ksf[4];
  #pragma unroll
  for (int h = 0; h < 4; ++h){
    kvf[h][0] = *(const short8*)(kvFb + (h*3 + 0)*512 + lane*8);
    kvf[h][1] = *(const short8*)(kvFb + (h*3 + 1)*512 + lane*8);
    ksf[h]    = *(const short8*)(kvFb + (h*3 + 2)*512 + lane*8);
  }
  short8 qf[2][4];
  #pragma unroll
  for (int nt = 0; nt < 2; ++nt)
    #pragma unroll
    for (int h = 0; h < 4; ++h)
      qf[nt][h] = *(const short8*)(qT + ((size_t)(b*HW_ + n0 + w*32 + nt*16 + lr))*128 + h*32 + lk*8);
  #pragma unroll
  for (int nt = 0; nt < 2; ++nt){
    int n_local = w*32 + nt*16 + lr;
    #pragma unroll
    for (int h = 0; h < 4; ++h){
      floatx4 z = {0.f,0.f,0.f,0.f};
      floatx4 dn = __builtin_amdgcn_mfma_f32_16x16x32_bf16(ksf[h],    qf[nt][h], z, 0,0,0);
      floatx4 p0 = __builtin_amdgcn_mfma_f32_16x16x32_bf16(kvf[h][0], qf[nt][h], z, 0,0,0);
      floatx4 p1 = __builtin_amdgcn_mfma_f32_16x16x32_bf16(kvf[h][1], qf[nt][h], z, 0,0,0);
      float inv = 1.f / (dn[0] + 1e-6f);
      short4v o0, o1;
      #pragma unroll
      for (int r = 0; r < 4; ++r){ o0[r] = (short)f2bf(p0[r]*inv); o1[r] = (short)f2bf(p1[r]*inv); }
      int c0 = h*32 + lk*4;
      *(short4v*)(aS + n_local*128 + (((c0 >> 3) ^ (n_local & 7)) << 3) + (c0 & 7)) = o0;
      int c1 = c0 + 16;
      *(short4v*)(aS + n_local*128 + (((c1 >> 3) ^ (n_local & 7)) << 3) + (c1 & 7)) = o1;
    }
  }
  __syncthreads();

  // ---- phase 2: h = w_out @ attn (MFMA), write bf16, GN2 partial stats ----
  short8 afr[4];
  #pragma unroll
  for (int ks = 0; ks < 4; ++ks)
    afr[ks] = *(const short8*)(woutb + (size_t)(w*16 + lr)*128 + ks*32 + lk*8);
  float gs[4] = {0,0,0,0}, gq[4] = {0,0,0,0};
  for (int ct = 0; ct < 16; ++ct){
    int nr = ct*16 + lr;
    short8 bfr[4];
    #pragma unroll
    for (int ks = 0; ks < 4; ++ks)
      bfr[ks] = *(const short8*)(aS + nr*128 + (((ks*4 + lk) ^ (nr & 7)) << 3));
    floatx4 acc = {0.f, 0.f, 0.f, 0.f};
    #pragma unroll
    for (int ks = 0; ks < 4; ++ks)
      acc = __builtin_amdgcn_mfma_f32_16x16x32_bf16(afr[ks], bfr[ks], acc, 0, 0, 0);
    int nn = n0 + ct*16 + lr;
    #pragma unroll
    for (int r = 0; r < 4; ++r){
      float hv = acc[r];
      hb[((size_t)b*128 + w*16 + lk*4 + r) * HW_ + nn] = f2bf(hv);
      gs[r] += hv; gq[r] += hv * hv;
    }
  }
  #pragma unroll
  for (int m = 1; m < 16; m <<= 1){
    #pragma unroll
    for (int r = 0; r < 4; ++r){ gs[r] += __shfl_xor(gs[r], m); gq[r] += __shfl_xor(gq[r], m); }
  }
  if (lr == 0){
    #pragma unroll
    for (int r = 0; r < 4; ++r){
      int o = w*16 + lk*4 + r;
      gn2part[((size_t)blk*128 + o)*2 + 0] = gs[r];
      gn2part[((size_t)blk*128 + o)*2 + 1] = gq[r];
    }
  }
}

// ------- K5: GN2 stats -------
__global__ __launch_bounds__(64) void k_gn2stats(const float* __restrict__ gn2part,
    float* __restrict__ mean, float* __restrict__ rstd){
  int b = blockIdx.x >> 5, g = blockIdx.x & 31;
  int lane = threadIdx.x;
  float s = 0.f, s2 = 0.f;
  #pragma unroll
  for (int j = 0; j < 4; ++j){
    const float* p = gn2part + (((size_t)(b*64 + lane))*128 + g*4 + j)*2;
    s += p[0]; s2 += p[1];
  }
  #pragma unroll
  for (int o = 32; o; o >>= 1){ s += __shfl_down(s, o); s2 += __shfl_down(s2, o); }
  if (lane == 0){
    float m = s * (1.f / 65536.f);
    float var = s2 * (1.f / 65536.f) - m * m;
    mean[blockIdx.x] = m;
    rstd[blockIdx.x] = rsqrtf(var + 1e-5f);
  }
}

// ------- K6: out = GN2(h) + x  (h is bf16 in ws, out is f32 d_out) -------
__global__ __launch_bounds__(256) void k_final(const unsigned short* __restrict__ hb, const float* __restrict__ x,
    float* __restrict__ out,
    const float* __restrict__ mean, const float* __restrict__ rstd,
    const float* __restrict__ g2w, const float* __restrict__ g2b){
  for (size_t chunk = (size_t)blockIdx.x*256 + threadIdx.x; chunk < 4194304ull; chunk += (size_t)2048*256){
    size_t base = chunk * 8;
    int c  = (int)((base >> 14) & 127);
    int bg = (int)(base >> 21) * 32 + (c >> 2);
    float m = mean[bg], r = rstd[bg];
    float sc = r * g2w[c], sh = g2b[c] - m * sc;
    short8 hv = *(const short8*)(hb + base);
    const float4* xp = (const float4*)(x + base);
    float4 x0 = xp[0], x1 = xp[1];
    float4 o0, o1;
    o0.x = bf2f((unsigned short)hv[0])*sc + sh + x0.x;
    o0.y = bf2f((unsigned short)hv[1])*sc + sh + x0.y;
    o0.z = bf2f((unsigned short)hv[2])*sc + sh + x0.z;
    o0.w = bf2f((unsigned short)hv[3])*sc + sh + x0.w;
    o1.x = bf2f((unsigned short)hv[4])*sc + sh + x1.x;
    o1.y = bf2f((unsigned short)hv[5])*sc + sh + x1.y;
    o1.z = bf2f((unsigned short)hv[6])*sc + sh + x1.z;
    o1.w = bf2f((unsigned short)hv[7])*sc + sh + x1.w;
    float4* op = (float4*)(out + base);
    op[0] = o0; op[1] = o1;
  }
}

extern "C" void kernel_launch(void* const* d_in, const int* in_sizes, int n_in,
                              void* d_out, int out_size, void* d_ws, size_t ws_size,
                              hipStream_t stream){
  const float* x    = (const float*)d_in[0];
  const float* g1w  = (const float*)d_in[1];
  const float* g1b  = (const float*)d_in[2];
  const float* wqkv = (const float*)d_in[3];
  const float* wout = (const float*)d_in[4];
  const float* g2w  = (const float*)d_in[5];
  const float* g2b  = (const float*)d_in[6];
  char* ws = (char*)d_ws;
  (void)in_sizes; (void)n_in; (void)out_size; (void)ws_size;

  float* gn1_mean = (float*)(ws + 0);
  float* gn1_rstd = (float*)(ws + 2048);
  float* gn2_mean = (float*)(ws + 4096);
  float* gn2_rstd = (float*)(ws + 6144);
  float* bias     = (float*)(ws + 8192);                     // 16*384 f32 -> ends 32768
  unsigned short* woutb = (unsigned short*)(ws + 32768);     // 32KB -> ends 65536
  unsigned short* kvF   = (unsigned short*)(ws + 65536);     // 16*4*3*512 bf16 = 196608 -> ends 262144
  unsigned short* wqp   = (unsigned short*)(ws + 262144);    // 1.5MB -> ends 1835008
  float* ksumpart = (float*)(ws + 1835008);                  // 16*4*32*32 f32 = 256KB -> ends 2097152
  float* kvpart   = (float*)(ws + 2097152);                  // 16*4*32*1024 f32 = 8MB -> ends 10485760
  float* gn2part  = (float*)(ws + 10485760);                 // 1MB -> ends 11534336
  unsigned short* qT = (unsigned short*)(ws + 11534336);     // 64MB -> ends 78643200
  unsigned short* kG = (unsigned short*)(ws + 78643200);     // 64MB -> ends 145752064
  unsigned short* vG = (unsigned short*)(ws + 145752064);    // 64MB -> ends 212860928
  unsigned short* hb = (unsigned short*)(ws + 78643200);     // aliases kG (dead after k_kvred)

  k_gn1<<<dim3(512), dim3(256), 0, stream>>>(x, gn1_mean, gn1_rstd);
  k_fold<<<dim3(6272), dim3(64), 0, stream>>>(wqkv, wout, g1w, g1b, gn1_mean, gn1_rstd, wqp, bias, woutb);
  k_qkv<<<dim3(1024), dim3(512), 0, stream>>>(x, wqp, bias, qT, kG, vG);
  k_kvred<<<dim3(512), dim3(256), 0, stream>>>(kG, vG, kvpart, ksumpart);
  k_kvfin<<<dim3(64), dim3(256), 0, stream>>>(kvpart, ksumpart, kvF);
  k_attn<<<dim3(1024), dim3(512), 0, stream>>>(qT, kvF, woutb, hb, gn2part);
  k_gn2stats<<<dim3(512), dim3(64), 0, stream>>>(gn2part, gn2_mean, gn2_rstd);
  k_final<<<dim3(2048), dim3(256), 0, stream>>>(hb, x, (float*)d_out, gn2_mean, gn2_rstd, g2w, g2b);
}

// Round 3
// 223.777 us; speedup vs baseline: 1.6954x; 1.2525x over previous
//
#include <hip/hip_runtime.h>

#define B_   16
#define C_   128
#define HW_  16384

typedef __attribute__((ext_vector_type(4))) float  floatx4;
typedef __attribute__((ext_vector_type(8))) short  short8;
typedef __attribute__((ext_vector_type(4))) short  short4v;

static __device__ __forceinline__ unsigned short f2bf(float f){
  unsigned int u = __float_as_uint(f);
  u += 0x7FFFu + ((u >> 16) & 1u);
  return (unsigned short)(u >> 16);
}
static __device__ __forceinline__ float bf2f(unsigned short h){
  return __uint_as_float(((unsigned int)h) << 16);
}
static __device__ __forceinline__ float elu1(float v){
  return v > 0.f ? v + 1.f : __expf(v);
}
// xT swizzle key: reads (rows 16ct+lr) get 8 distinct quads via bits 1-3;
// xprep writes (rows 4l+i) get spread via bits 2-7 through the >>4 term.
static __device__ __forceinline__ int keyx(int n){ return ((n >> 1) & 7) ^ ((n >> 4) & 7); }

// ---- K1: x -> xT (bf16, tile-major [b][tile256][n][c] pre-swizzled LDS image) + GN1 partial stats ----
__global__ __launch_bounds__(512) void k_xprep(const float* __restrict__ x,
    unsigned short* __restrict__ xT, float* __restrict__ gn1part){
  int blk = blockIdx.x;                        // b*64 + tile
  int b = blk >> 6, tile = blk & 63;
  int n0 = tile * 256;
  __shared__ unsigned short XS[32768];         // [256 n][128 c] bf16, swizzled 16B slots
  int t = threadIdx.x, w = t >> 6, l = t & 63;
  float sk[4], sk2[4];
  #pragma unroll
  for (int k = 0; k < 4; ++k){ sk[k] = 0.f; sk2[k] = 0.f; }
  #pragma unroll
  for (int k = 0; k < 4; ++k){
    float4 f4[4];
    #pragma unroll
    for (int j = 0; j < 4; ++j){
      int c = 16*w + 4*k + j;                  // wave-uniform channel
      f4[j] = *(const float4*)(x + ((size_t)(b*128 + c))*HW_ + n0 + 4*l);
    }
    #pragma unroll
    for (int j = 0; j < 4; ++j){
      sk[k]  += f4[j].x + f4[j].y + f4[j].z + f4[j].w;
      sk2[k] += f4[j].x*f4[j].x + f4[j].y*f4[j].y + f4[j].z*f4[j].z + f4[j].w*f4[j].w;
    }
    int c0 = 16*w + 4*k, cs = c0 >> 3, co = c0 & 7;
    #pragma unroll
    for (int i = 0; i < 4; ++i){               // 4x4 in-register transpose
      int n = 4*l + i;
      short4v p;
      #pragma unroll
      for (int j = 0; j < 4; ++j) p[j] = (short)f2bf(((const float*)&f4[j])[i]);
      *(short4v*)(XS + n*128 + (((cs ^ keyx(n)) << 3) + co)) = p;
    }
  }
  #pragma unroll
  for (int k = 0; k < 4; ++k){                 // group g = 4w + k, uniform per wave
    float a = sk[k], q = sk2[k];
    #pragma unroll
    for (int o = 32; o; o >>= 1){ a += __shfl_down(a, o); q += __shfl_down(q, o); }
    if (l == 0){
      gn1part[((size_t)blk)*64 + (4*w + k)*2 + 0] = a;
      gn1part[((size_t)blk)*64 + (4*w + k)*2 + 1] = q;
    }
  }
  __syncthreads();
  unsigned short* dst = xT + ((size_t)blk)*32768;
  for (int it = 0; it < 8; ++it){              // linear copyout, fully coalesced
    int slot = t + it*512;
    *(short8*)(dst + slot*8) = *(const short8*)(XS + slot*8);
  }
}

// ---- K1f: finalize GN1 stats ----
__global__ __launch_bounds__(64) void k_gn1fin(const float* __restrict__ gn1part,
    float* __restrict__ mean, float* __restrict__ rstd){
  int bg = blockIdx.x;                         // b*32 + g
  int b = bg >> 5, g = bg & 31, l = threadIdx.x;
  const float* p = gn1part + ((size_t)(b*64 + l))*64 + g*2;
  float s = p[0], s2 = p[1];
  #pragma unroll
  for (int o = 32; o; o >>= 1){ s += __shfl_down(s, o); s2 += __shfl_down(s2, o); }
  if (l == 0){
    float m = s * (1.f/65536.f);
    float var = s2 * (1.f/65536.f) - m*m;
    mean[bg] = m; rstd[bg] = rsqrtf(var + 1e-5f);
  }
}

// ---- K2: fold GN1 into qkv weights (per batch), w_out -> bf16 ----
__global__ __launch_bounds__(64) void k_fold(const float* __restrict__ wqkv, const float* __restrict__ wout,
    const float* __restrict__ g1w, const float* __restrict__ g1b,
    const float* __restrict__ mean, const float* __restrict__ rstd,
    unsigned short* __restrict__ wqp, float* __restrict__ bias, unsigned short* __restrict__ woutb){
  int i = blockIdx.x, l = threadIdx.x;
  if (i < 6144){
    int b = i / 384, o = i % 384;
    float bsum = 0.f;
    #pragma unroll
    for (int j = 0; j < 2; ++j){
      int c = l*2 + j, g = c >> 2;
      float m = mean[b*32 + g], r = rstd[b*32 + g];
      float A  = r * g1w[c];
      float Bc = g1b[c] - m * A;
      float wv = wqkv[o*128 + c];
      wqp[((size_t)(b*384 + o))*128 + c] = f2bf(wv * A);
      bsum += wv * Bc;
    }
    #pragma unroll
    for (int o2 = 32; o2; o2 >>= 1) bsum += __shfl_down(bsum, o2);
    if (l == 0) bias[b*384 + o] = bsum;
  } else {
    int r = i - 6144;
    #pragma unroll
    for (int j = 0; j < 2; ++j){ int c = l*2 + j; woutb[r*128 + c] = f2bf(wout[r*128 + c]); }
  }
}

// ---- K3: k,v GEMM from xT + in-LDS kv/ksum reduction (no kG/vG globals) ----
__global__ __launch_bounds__(512) void k_kv(const unsigned short* __restrict__ xT,
    const unsigned short* __restrict__ wqp, const float* __restrict__ bias,
    float* __restrict__ kvpart, float* __restrict__ ksumpart){
  int blk = blockIdx.x;                        // b*128 + nt (128-n tile)
  int b = blk >> 7, nt = blk & 127;
  __shared__ unsigned short S[32768];          // 64KB: [0,16384)=xTile then kImg; [16384,32768)=vImg
  int t = threadIdx.x, w = t >> 6, lane = t & 63, lr = lane & 15, lk = lane >> 4;
  const unsigned short* src = xT + ((size_t)(b*64 + (nt >> 1)))*32768 + (nt & 1)*16384;
  for (int it = 0; it < 4; ++it){
    int slot = t + it*512;
    *(short8*)(S + slot*8) = *(const short8*)(src + slot*8);
  }
  __syncthreads();
  short8 afr[2][4]; float biasr[2][4];
  #pragma unroll
  for (int rt = 0; rt < 2; ++rt){
    int o = 128 + rt*128 + w*16;
    #pragma unroll
    for (int ks = 0; ks < 4; ++ks)
      afr[rt][ks] = *(const short8*)(wqp + ((size_t)(b*384 + o + lr))*128 + ks*32 + lk*8);
    #pragma unroll
    for (int r = 0; r < 4; ++r) biasr[rt][r] = bias[b*384 + o + lk*4 + r];
  }
  short4v kpk[8], vpk[8];
  for (int ct = 0; ct < 8; ++ct){
    int nr = ct*16 + lr;
    int kn = keyx(nr);
    short8 bfr[4];
    #pragma unroll
    for (int ks = 0; ks < 4; ++ks)
      bfr[ks] = *(const short8*)(S + nr*128 + (((ks*4 + lk) ^ kn) << 3));
    #pragma unroll
    for (int rt = 0; rt < 2; ++rt){
      floatx4 acc = {0.f,0.f,0.f,0.f};
      #pragma unroll
      for (int ks = 0; ks < 4; ++ks)
        acc = __builtin_amdgcn_mfma_f32_16x16x32_bf16(afr[rt][ks], bfr[ks], acc, 0,0,0);
      short4v pk;
      #pragma unroll
      for (int r = 0; r < 4; ++r){
        float v = acc[r] + biasr[rt][r];
        if (rt == 0) v = elu1(v);
        pk[r] = (short)f2bf(v);
      }
      if (rt == 0) kpk[ct] = pk; else vpk[ct] = pk;
    }
  }
  __syncthreads();
  // build k/v images [128 c][128 n] bf16 (key=(c>>1)&7), overwriting xTile
  for (int ct = 0; ct < 8; ++ct){
    int n = ct*16 + lr;
    #pragma unroll
    for (int r = 0; r < 4; ++r){
      int c = w*16 + lk*4 + r;
      int key = (c >> 1) & 7;
      int off = c*128 + ((((n >> 3) ^ key) << 3) + (n & 7));
      S[off]         = (unsigned short)kpk[ct][r];
      S[16384 + off] = (unsigned short)vpk[ct][r];
    }
  }
  __syncthreads();
  short8 ones;
  #pragma unroll
  for (int j = 0; j < 8; ++j) ones[j] = (short)0x3F80;
  #pragma unroll
  for (int j = 0; j < 2; ++j){
    int m = w + 8*j;                           // 16 tasks: h x dt x et
    int h = m >> 2, dt = (m >> 1) & 1, et = m & 1;
    int arow = h*32 + dt*16 + lr, brow = h*32 + et*16 + lr;
    int akey = (lr >> 1) & 7;
    floatx4 acc = {0.f,0.f,0.f,0.f}, ks_acc = {0.f,0.f,0.f,0.f};
    #pragma unroll
    for (int ks = 0; ks < 4; ++ks){
      short8 ka = *(const short8*)(S + arow*128 + (((ks*4 + lk) ^ akey) << 3));
      short8 vb = *(const short8*)(S + 16384 + brow*128 + (((ks*4 + lk) ^ akey) << 3));
      acc = __builtin_amdgcn_mfma_f32_16x16x32_bf16(ka, vb, acc, 0,0,0);
      if (et == 0) ks_acc = __builtin_amdgcn_mfma_f32_16x16x32_bf16(ka, ones, ks_acc, 0,0,0);
    }
    float* kvp = kvpart + ((size_t)((b*128 + nt)*4 + h))*1024;
    #pragma unroll
    for (int r = 0; r < 4; ++r)
      kvp[(dt*16 + lk*4 + r)*32 + et*16 + lr] = acc[r];
    if (et == 0 && lr == 0){
      float* ksp = ksumpart + ((size_t)((b*128 + nt)*4 + h))*32;
      #pragma unroll
      for (int r = 0; r < 4; ++r) ksp[dt*16 + lk*4 + r] = ks_acc[r];
    }
  }
}

// ---- K3f: reduce kv/ksum partials, emit bf16 MFMA A-fragments ----
__global__ __launch_bounds__(256) void k_kvfin(const float* __restrict__ kvpart, const float* __restrict__ ksumpart,
    unsigned short* __restrict__ kvF){
  int bh = blockIdx.x, t = threadIdx.x;        // 64 = (b, h)
  int b = bh >> 2, h = bh & 3;
  __shared__ float kvL[1024];
  __shared__ float ksumL[32];
  for (int i = t; i < 1024; i += 256){
    float s = 0.f;
    for (int nt = 0; nt < 128; ++nt) s += kvpart[((size_t)((b*128 + nt)*4 + h))*1024 + i];
    kvL[i] = s;
  }
  if (t < 32){
    float s = 0.f;
    for (int nt = 0; nt < 128; ++nt) s += ksumpart[((size_t)((b*128 + nt)*4 + h))*32 + t];
    ksumL[t] = s;
  }
  __syncthreads();
  for (int idx = t; idx < 3*512; idx += 256){
    int f = idx >> 9, rem = idx & 511;
    int lane = rem >> 3, j = rem & 7;
    int d = (lane >> 4)*8 + j;
    float v = (f < 2) ? kvL[d*32 + f*16 + (lane & 15)] : ksumL[d];
    kvF[(size_t)(bh*3 + f)*512 + rem] = f2bf(v);
  }
}

// ---- K4: q GEMM from xT -> attention (MFMA) -> w_out GEMM -> h(bf16) + GN2 partials ----
__global__ __launch_bounds__(512) void k_attn2(const unsigned short* __restrict__ xT,
    const unsigned short* __restrict__ wqp, const float* __restrict__ bias,
    const unsigned short* __restrict__ kvF, const unsigned short* __restrict__ woutb,
    unsigned short* __restrict__ hb, float* __restrict__ gn2part){
  int blk = blockIdx.x;                        // b*64 + tile256
  int b = blk >> 6;
  int n0 = (blk & 63) * 256;
  __shared__ unsigned short S[32768];          // 64KB: xTile, then aS [256 n][128 c] (key n&7)
  int t = threadIdx.x, w = t >> 6, lane = t & 63, lr = lane & 15, lk = lane >> 4;
  const unsigned short* src = xT + ((size_t)blk)*32768;
  for (int it = 0; it < 8; ++it){
    int slot = t + it*512;
    *(short8*)(S + slot*8) = *(const short8*)(src + slot*8);
  }
  short8 afr[4]; float biasq[4];
  #pragma unroll
  for (int ks = 0; ks < 4; ++ks)
    afr[ks] = *(const short8*)(wqp + ((size_t)(b*384 + w*16 + lr))*128 + ks*32 + lk*8);
  #pragma unroll
  for (int r = 0; r < 4; ++r) biasq[r] = bias[b*384 + w*16 + lk*4 + r];
  __syncthreads();
  // q-GEMM: wave w covers q rows o = 16w..16w+15
  short4v qpk[16];
  for (int ct = 0; ct < 16; ++ct){
    int nr = ct*16 + lr;
    int kn = keyx(nr);
    short8 bfr[4];
    #pragma unroll
    for (int ks = 0; ks < 4; ++ks)
      bfr[ks] = *(const short8*)(S + nr*128 + (((ks*4 + lk) ^ kn) << 3));
    floatx4 acc = {0.f,0.f,0.f,0.f};
    #pragma unroll
    for (int ks = 0; ks < 4; ++ks)
      acc = __builtin_amdgcn_mfma_f32_16x16x32_bf16(afr[ks], bfr[ks], acc, 0,0,0);
    short4v pk;
    #pragma unroll
    for (int r = 0; r < 4; ++r) pk[r] = (short)f2bf(elu1(acc[r] + biasq[r]));
    qpk[ct] = pk;
  }
  __syncthreads();
  // write q into aS [n][c], key = n&7
  for (int ct = 0; ct < 16; ++ct){
    int n = ct*16 + lr;
    int c0 = w*16 + lk*4;
    *(short4v*)(S + n*128 + ((((c0 >> 3) ^ (n & 7)) << 3) + (c0 & 7))) = qpk[ct];
  }
  // load kv fragments while q lands
  const unsigned short* kvFb = kvF + (size_t)b * 12 * 512;
  short8 kvf[4][2], ksf[4];
  #pragma unroll
  for (int h = 0; h < 4; ++h){
    kvf[h][0] = *(const short8*)(kvFb + (h*3 + 0)*512 + lane*8);
    kvf[h][1] = *(const short8*)(kvFb + (h*3 + 1)*512 + lane*8);
    ksf[h]    = *(const short8*)(kvFb + (h*3 + 2)*512 + lane*8);
  }
  __syncthreads();
  // attention: wave w owns n-rows 32w..32w+31 (reads q, overwrites with attn-out)
  short8 qf[2][4];
  #pragma unroll
  for (int nt = 0; nt < 2; ++nt){
    int n = w*32 + nt*16 + lr;
    #pragma unroll
    for (int h = 0; h < 4; ++h)
      qf[nt][h] = *(const short8*)(S + n*128 + (((4*h + lk) ^ (n & 7)) << 4) / 2);
  }
  #pragma unroll
  for (int nt = 0; nt < 2; ++nt){
    int n_local = w*32 + nt*16 + lr;
    #pragma unroll
    for (int h = 0; h < 4; ++h){
      floatx4 z = {0.f,0.f,0.f,0.f};
      floatx4 dn = __builtin_amdgcn_mfma_f32_16x16x32_bf16(ksf[h],    qf[nt][h], z, 0,0,0);
      floatx4 p0 = __builtin_amdgcn_mfma_f32_16x16x32_bf16(kvf[h][0], qf[nt][h], z, 0,0,0);
      floatx4 p1 = __builtin_amdgcn_mfma_f32_16x16x32_bf16(kvf[h][1], qf[nt][h], z, 0,0,0);
      float inv = 1.f / (dn[0] + 1e-6f);
      short4v o0, o1;
      #pragma unroll
      for (int r = 0; r < 4; ++r){ o0[r] = (short)f2bf(p0[r]*inv); o1[r] = (short)f2bf(p1[r]*inv); }
      int c0 = h*32 + lk*4;
      *(short4v*)(S + n_local*128 + ((((c0 >> 3) ^ (n_local & 7)) << 3) + (c0 & 7))) = o0;
      int c1 = c0 + 16;
      *(short4v*)(S + n_local*128 + ((((c1 >> 3) ^ (n_local & 7)) << 3) + (c1 & 7))) = o1;
    }
  }
  __syncthreads();
  // w_out GEMM
  short8 afr2[4];
  #pragma unroll
  for (int ks = 0; ks < 4; ++ks)
    afr2[ks] = *(const short8*)(woutb + (size_t)(w*16 + lr)*128 + ks*32 + lk*8);
  float gs[4] = {0,0,0,0}, gq[4] = {0,0,0,0};
  for (int ct = 0; ct < 16; ++ct){
    int nr = ct*16 + lr;
    short8 bfr[4];
    #pragma unroll
    for (int ks = 0; ks < 4; ++ks)
      bfr[ks] = *(const short8*)(S + nr*128 + (((ks*4 + lk) ^ (nr & 7)) << 3));
    floatx4 acc = {0.f,0.f,0.f,0.f};
    #pragma unroll
    for (int ks = 0; ks < 4; ++ks)
      acc = __builtin_amdgcn_mfma_f32_16x16x32_bf16(afr2[ks], bfr[ks], acc, 0,0,0);
    int nn = n0 + ct*16 + lr;
    #pragma unroll
    for (int r = 0; r < 4; ++r){
      float hv = acc[r];
      hb[((size_t)b*128 + w*16 + lk*4 + r) * HW_ + nn] = f2bf(hv);
      gs[r] += hv; gq[r] += hv * hv;
    }
  }
  #pragma unroll
  for (int m = 1; m < 16; m <<= 1){
    #pragma unroll
    for (int r = 0; r < 4; ++r){ gs[r] += __shfl_xor(gs[r], m); gq[r] += __shfl_xor(gq[r], m); }
  }
  if (lr == 0){
    #pragma unroll
    for (int r = 0; r < 4; ++r){
      int o = w*16 + lk*4 + r;
      gn2part[((size_t)blk*128 + o)*2 + 0] = gs[r];
      gn2part[((size_t)blk*128 + o)*2 + 1] = gq[r];
    }
  }
}

// ---- K5: GN2 stats ----
__global__ __launch_bounds__(64) void k_gn2stats(const float* __restrict__ gn2part,
    float* __restrict__ mean, float* __restrict__ rstd){
  int b = blockIdx.x >> 5, g = blockIdx.x & 31;
  int lane = threadIdx.x;
  float s = 0.f, s2 = 0.f;
  #pragma unroll
  for (int j = 0; j < 4; ++j){
    const float* p = gn2part + (((size_t)(b*64 + lane))*128 + g*4 + j)*2;
    s += p[0]; s2 += p[1];
  }
  #pragma unroll
  for (int o = 32; o; o >>= 1){ s += __shfl_down(s, o); s2 += __shfl_down(s2, o); }
  if (lane == 0){
    float m = s * (1.f/65536.f);
    float var = s2 * (1.f/65536.f) - m*m;
    mean[blockIdx.x] = m; rstd[blockIdx.x] = rsqrtf(var + 1e-5f);
  }
}

// ---- K6: out = GN2(h) + x ----
__global__ __launch_bounds__(256) void k_final(const unsigned short* __restrict__ hb, const float* __restrict__ x,
    float* __restrict__ out,
    const float* __restrict__ mean, const float* __restrict__ rstd,
    const float* __restrict__ g2w, const float* __restrict__ g2b){
  for (size_t chunk = (size_t)blockIdx.x*256 + threadIdx.x; chunk < 4194304ull; chunk += (size_t)2048*256){
    size_t base = chunk * 8;
    int c  = (int)((base >> 14) & 127);
    int bg = (int)(base >> 21) * 32 + (c >> 2);
    float m = mean[bg], r = rstd[bg];
    float sc = r * g2w[c], sh = g2b[c] - m * sc;
    short8 hv = *(const short8*)(hb + base);
    const float4* xp = (const float4*)(x + base);
    float4 x0 = xp[0], x1 = xp[1];
    float4 o0, o1;
    o0.x = bf2f((unsigned short)hv[0])*sc + sh + x0.x;
    o0.y = bf2f((unsigned short)hv[1])*sc + sh + x0.y;
    o0.z = bf2f((unsigned short)hv[2])*sc + sh + x0.z;
    o0.w = bf2f((unsigned short)hv[3])*sc + sh + x0.w;
    o1.x = bf2f((unsigned short)hv[4])*sc + sh + x1.x;
    o1.y = bf2f((unsigned short)hv[5])*sc + sh + x1.y;
    o1.z = bf2f((unsigned short)hv[6])*sc + sh + x1.z;
    o1.w = bf2f((unsigned short)hv[7])*sc + sh + x1.w;
    float4* op = (float4*)(out + base);
    op[0] = o0; op[1] = o1;
  }
}

extern "C" void kernel_launch(void* const* d_in, const int* in_sizes, int n_in,
                              void* d_out, int out_size, void* d_ws, size_t ws_size,
                              hipStream_t stream){
  const float* x    = (const float*)d_in[0];
  const float* g1w  = (const float*)d_in[1];
  const float* g1b  = (const float*)d_in[2];
  const float* wqkv = (const float*)d_in[3];
  const float* wout = (const float*)d_in[4];
  const float* g2w  = (const float*)d_in[5];
  const float* g2b  = (const float*)d_in[6];
  char* ws = (char*)d_ws;
  (void)in_sizes; (void)n_in; (void)out_size; (void)ws_size;

  float* gn1part  = (float*)(ws + 0);                        // 1024*64*4 = 256KB
  float* gn1_mean = (float*)(ws + 262144);
  float* gn1_rstd = (float*)(ws + 264192);
  float* gn2_mean = (float*)(ws + 266240);
  float* gn2_rstd = (float*)(ws + 268288);
  float* bias     = (float*)(ws + 270336);                   // 24KB
  unsigned short* woutb = (unsigned short*)(ws + 294912);    // 32KB
  unsigned short* kvF   = (unsigned short*)(ws + 327680);    // 192KB
  unsigned short* wqp   = (unsigned short*)(ws + 524288);    // 1.5MB
  float* ksumpart = (float*)(ws + 2097152);                  // 1MB
  float* kvpart   = (float*)(ws + 3145728);                  // 32MB
  float* gn2part  = (float*)(ws + 36700160);                 // 1MB
  unsigned short* xT = (unsigned short*)(ws + 37748736);     // 64MB
  unsigned short* hb = (unsigned short*)(ws + 104857600);    // 64MB  (total ~172MB)

  k_xprep<<<dim3(1024), dim3(512), 0, stream>>>(x, xT, gn1part);
  k_gn1fin<<<dim3(512), dim3(64), 0, stream>>>(gn1part, gn1_mean, gn1_rstd);
  k_fold<<<dim3(6272), dim3(64), 0, stream>>>(wqkv, wout, g1w, g1b, gn1_mean, gn1_rstd, wqp, bias, woutb);
  k_kv<<<dim3(2048), dim3(512), 0, stream>>>(xT, wqp, bias, kvpart, ksumpart);
  k_kvfin<<<dim3(64), dim3(256), 0, stream>>>(kvpart, ksumpart, kvF);
  k_attn2<<<dim3(1024), dim3(512), 0, stream>>>(xT, wqp, bias, kvF, woutb, hb, gn2part);
  k_gn2stats<<<dim3(512), dim3(64), 0, stream>>>(gn2part, gn2_mean, gn2_rstd);
  k_final<<<dim3(2048), dim3(256), 0, stream>>>(hb, x, (float*)d_out, gn2_mean, gn2_rstd, g2w, g2b);
}